// Round 4
// baseline (135.264 us; speedup 1.0000x reference)
//
#include <hip/hip_runtime.h>
#include <math.h>

#define N      4096
#define BLOCK  256
#define JW     32                  // j-tile width
#define NITILE (N / BLOCK)         // 16 i-tiles (256 rows each)
#define NTRI   1088                // sum_{t=0..15} (128 - 8t)

// s(e) = sum_k 1/(1 + c_k*e), c_k = e^{-t_k}, t = {0.5,1,2,4} = Pn(e)/Pd(e)
#define PN0 4.0f
#define PN1 3.384183069f
#define PN2 0.750655861f
#define PN3 0.036699475f
#define PD1 1.128061023f
#define PD2 0.375327930f
#define PD3 0.036699475f
#define PD4 0.000553084f

// ws layout (float/int view): [0] = ticket counter (int), [16 + 2k] = num_k,
// [17 + 2k] = den_k.  First 128 B zeroed by a memset node each launch.
#define WS_CTR   0
#define WS_ACC   16

__device__ __forceinline__ int tri_off(int t) { return 132 * t - 4 * t * t; }

__global__ __launch_bounds__(BLOCK, 8) void lddt_main_kernel(
    const float* __restrict__ pred, const float* __restrict__ truec,
    const int* __restrict__ is_dna, const int* __restrict__ is_rna,
    const int* __restrict__ cmask, float* __restrict__ ws,
    float* __restrict__ out, int nblk_total, int b)
{
    const int L     = blockIdx.x;     // 0..NTRI-1
    const int batch = blockIdx.z;
    const int tid   = threadIdx.x;

    int itile = 0;
#pragma unroll
    for (int u = 1; u < NITILE; ++u) itile += (L >= tri_off(u)) ? 1 : 0;
    const int jseg = 8 * itile + (L - tri_off(itile));
    const bool diag = (jseg < 8 * itile + 8);   // j-range overlaps i-range

    const int i = itile * BLOCK + tid;

    const float* pb = pred  + (size_t)batch * N * 3;
    const float* tb = truec + (size_t)batch * N * 3;
    const int* dnab = is_dna + (size_t)batch * N;
    const int* rnab = is_rna + (size_t)batch * N;
    const int* cmb  = cmask  + (size_t)batch * N;

    // jP = {px,py,pz, nuc?675:0}, jT = {tx,ty,tz, cm?1:0}
    __shared__ float4 jP[JW], jT[JW];
    const int j0 = jseg * JW;
    if (tid < JW) {
        const int j = j0 + tid;
        jP[tid] = make_float4(pb[j*3+0], pb[j*3+1], pb[j*3+2],
                              (dnab[j] | rnab[j]) ? 675.0f : 0.0f);
        jT[tid] = make_float4(tb[j*3+0], tb[j*3+1], tb[j*3+2],
                              cmb[j] ? 1.0f : 0.0f);
    }
    __syncthreads();

    const float pix = pb[i*3+0], piy = pb[i*3+1], piz = pb[i*3+2];
    const float tix = tb[i*3+0], tiy = tb[i*3+1], tiz = tb[i*3+2];
    const float inuc01 = (dnab[i] | rnab[i]) ? 1.0f : 0.0f;
    const float icm    = cmb[i] ? 1.0f : 0.0f;

    float num = 0.0f, den = 0.0f;

    // per-pair partial: nN (numer poly * mask applied later), nD, m
#define PAIR(K, NEED_TRI, NN, ND, M)                                           \
    {                                                                          \
        const float4 P = jP[K];                                                \
        const float4 T = jT[K];                                                \
        float dxp = pix - P.x, dyp = piy - P.y, dzp = piz - P.z;               \
        float d2p = fmaf(dxp, dxp, fmaf(dyp, dyp, dzp * dzp));                 \
        float dp  = __builtin_amdgcn_sqrtf(d2p);                               \
        float dxt = tix - T.x, dyt = tiy - T.y, dzt = tiz - T.z;               \
        float d2t = fmaf(dxt, dxt, fmaf(dyt, dyt, dzt * dzt));                 \
        float dt  = __builtin_amdgcn_sqrtf(d2t);                               \
        float dd  = fminf(fabsf(dt - dp), 10.0f);                              \
        float e   = __expf(dd);                                                \
        NN = fmaf(e, fmaf(e, fmaf(e, PN3, PN2), PN1), PN0);                    \
        ND = fmaf(e, fmaf(e, fmaf(e, fmaf(e, PD4, PD3), PD2), PD1), 1.0f);     \
        float cutsq = fmaf(inuc01, P.w, 225.0f);                               \
        bool keep = (d2t < cutsq);                                             \
        if (NEED_TRI) keep = keep && (j0 + (K) > i);                           \
        M = keep ? T.w : 0.0f;                                                 \
    }

#define PAIR2(JJ, NEED_TRI)                                                    \
    {                                                                          \
        float n1, d1, m1, n2, d2, m2;                                          \
        PAIR(JJ, NEED_TRI, n1, d1, m1)                                         \
        PAIR((JJ) + 1, NEED_TRI, n2, d2, m2)                                   \
        float t1 = m1 * n1, t2 = m2 * n2;                                      \
        float nm = fmaf(t1, d2, t2 * d1);                                      \
        num = fmaf(nm, __builtin_amdgcn_rcpf(d1 * d2), num);                   \
        den += m1 + m2;                                                        \
    }

    if (diag) {
#pragma unroll 2
        for (int jj = 0; jj < JW; jj += 2) PAIR2(jj, true)
    } else {
#pragma unroll 2
        for (int jj = 0; jj < JW; jj += 2) PAIR2(jj, false)
    }
#undef PAIR2
#undef PAIR

    // symmetry x2 and threshold-mean /4:  num *= 2/4, den *= 2; gate by cm_i
    num *= 0.5f * icm;
    den *= 2.0f * icm;

    for (int off = 32; off > 0; off >>= 1) {
        num += __shfl_down(num, off);
        den += __shfl_down(den, off);
    }
    __shared__ float rn[BLOCK / 64], rd[BLOCK / 64];
    const int wid = tid >> 6, lane = tid & 63;
    if (lane == 0) { rn[wid] = num; rd[wid] = den; }
    __syncthreads();

    if (tid == 0) {
        float tn = rn[0] + rn[1] + rn[2] + rn[3];
        float td = rd[0] + rd[1] + rd[2] + rd[3];
        atomicAdd(&ws[WS_ACC + 2 * batch + 0], tn);
        atomicAdd(&ws[WS_ACC + 2 * batch + 1], td);
        __threadfence();                         // adds visible before ticket
        int old = atomicAdd((int*)ws + WS_CTR, 1);
        if (old == nblk_total - 1) {             // last block: finalize
            __threadfence();
            float acc = 0.0f;
            for (int k = 0; k < b; ++k) {
                float nm = __hip_atomic_load(&ws[WS_ACC + 2 * k + 0],
                                             __ATOMIC_RELAXED, __HIP_MEMORY_SCOPE_AGENT);
                float dn = __hip_atomic_load(&ws[WS_ACC + 2 * k + 1],
                                             __ATOMIC_RELAXED, __HIP_MEMORY_SCOPE_AGENT);
                acc += nm / fmaxf(dn, 1.0f);
            }
            out[0] = 1.0f - acc / (float)b;
        }
    }
}

extern "C" void kernel_launch(void* const* d_in, const int* in_sizes, int n_in,
                              void* d_out, int out_size, void* d_ws, size_t ws_size,
                              hipStream_t stream) {
    const float* pred  = (const float*)d_in[0];
    const float* truec = (const float*)d_in[1];
    const int* is_dna  = (const int*)d_in[2];
    const int* is_rna  = (const int*)d_in[3];
    const int* cmask   = (const int*)d_in[4];
    float* out = (float*)d_out;
    float* ws  = (float*)d_ws;

    const int b = in_sizes[2] / N;

    // zero ticket counter + accumulators (ws is poisoned 0xAA before every launch)
    hipMemsetAsync(ws, 0, 128, stream);

    dim3 grid(NTRI, 1, b);   // 1088 x b = 2176 blocks -> 8.5 blocks/CU
    lddt_main_kernel<<<grid, BLOCK, 0, stream>>>(pred, truec, is_dna, is_rna,
                                                 cmask, ws, out, NTRI * b, b);
}